// Round 4
// baseline (1830.322 us; speedup 1.0000x reference)
//
#include <hip/hip_runtime.h>

#define N_NODES 10000
#define EMB     128
#define NE      320000
#define NE_TOT  330000   // + one self-loop per node
#define NB      256
#define NTT     200
#define RH      256
#define G3      768

typedef unsigned short u16;
typedef u16    u16x8  __attribute__((ext_vector_type(8)));
typedef __bf16 bf16x8 __attribute__((ext_vector_type(8)));
typedef float  f32x4  __attribute__((ext_vector_type(4)));

static __device__ __forceinline__ float bf2f(u16 u){
  unsigned int x = ((unsigned int)u) << 16;
  return __builtin_bit_cast(float, x);
}
static __device__ __forceinline__ u16 f2bf(float f){
  unsigned int x = __builtin_bit_cast(unsigned int, f);
  x += 0x7fffu + ((x >> 16) & 1u);
  return (u16)(x >> 16);
}

// ---------------- CSR build ----------------
__global__ void k_deg(const int* __restrict__ eidx, const float* __restrict__ ew,
                      int* __restrict__ deg, float* __restrict__ wsum){
  int i = blockIdx.x*256 + threadIdx.x;
  if(i >= NE) return;
  int d = eidx[NE + i];
  atomicAdd(&deg[d], 1);
  atomicAdd(&wsum[d], ew[i]);
}

__global__ __launch_bounds__(1024) void k_scan(const int* __restrict__ deg,
                      float* __restrict__ wsum, int* __restrict__ off){
  __shared__ int part[1024];
  int tid = threadIdx.x;
  int n0 = tid*10;
  int s = 0;
  for(int i=0;i<10;++i){ int n=n0+i; if(n<N_NODES) s += deg[n]+1; }
  part[tid] = s;
  for(int i=0;i<10;++i){
    int n=n0+i;
    if(n<N_NODES){ int d=deg[n]; wsum[n] = wsum[n] / (float)(d>1?d:1); }
  }
  __syncthreads();
  for(int st=1; st<1024; st<<=1){
    int v = (tid>=st) ? part[tid-st] : 0;
    __syncthreads();
    part[tid] += v;
    __syncthreads();
  }
  int base = tid ? part[tid-1] : 0;
  for(int i=0;i<10;++i){ int n=n0+i; if(n<N_NODES){ off[n]=base; base += deg[n]+1; } }
  if(tid==999) off[N_NODES] = base;
}

__global__ void k_scatter(const int* __restrict__ eidx, const float* __restrict__ ew,
                          const float* __restrict__ la, const int* __restrict__ off,
                          int* __restrict__ fill, int* __restrict__ csrs, float* __restrict__ csrw){
  int i = blockIdx.x*256 + threadIdx.x;
  if(i >= NE_TOT) return;
  int s, d; float w;
  if(i < NE){ s = eidx[i]; d = eidx[NE+i]; w = ew[i]; }
  else      { int n = i-NE; s=n; d=n; w = la[n]; }   // self-loop, weight = mean incoming
  int pos = off[d] + atomicAdd(&fill[d], 1);
  csrs[pos] = s; csrw[pos] = w;
}

// ---------------- MFMA GEMM: C = A @ W^T + bias ----------------
// AMODE: 0 = A f32 [M,K]; 1 = gather f32 (A[gidx]+remb[ridx], chunked rows);
//        2 = A bf16 [M,K].
// W: f32 [N,K] (torch Linear). OUTF32: write f32, else bf16.
// lens != null (proj): row=(b*NTT+t), t>=lens[b] -> bias only.
template<int AMODE, bool OUTF32>
__global__ __launch_bounds__(256) void k_gemm(
    const void* __restrict__ Av, const float* __restrict__ W, const float* __restrict__ bias,
    void* __restrict__ out,
    int M, int N, int K,
    const int* __restrict__ gidx, const int* __restrict__ ridx, const float* __restrict__ remb,
    int t0, int chk,
    const int* __restrict__ lens)
{
  int tid = threadIdx.x;
  int wid = tid >> 6, l = tid & 63;
  int lr = l & 15, lg = l >> 4;
  int bm = blockIdx.x*128 + wid*32;
  int bn = blockIdx.y*64;
  f32x4 acc[2][4] = {};
  int nk = K >> 5;
  for(int kt=0; kt<nk; ++kt){
    int k0 = kt*32 + lg*8;
    bf16x8 af[2];
    #pragma unroll
    for(int mi=0; mi<2; ++mi){
      int row = bm + mi*16 + lr;
      u16x8 v = {0,0,0,0,0,0,0,0};
      if(row < M){
        if constexpr(AMODE == 1){
          int b = row / chk, tt = row - b*chk;
          int gi = b*NTT + t0 + tt;
          const float* ar = (const float*)Av + (size_t)gidx[gi]*K + k0;
          const float* rr = remb + (size_t)ridx[gi]*K + k0;
          #pragma unroll
          for(int e=0;e<8;++e) v[e] = f2bf(ar[e] + rr[e]);
        } else if constexpr(AMODE == 0){
          const float* ar = (const float*)Av + (size_t)row*K + k0;
          #pragma unroll
          for(int e=0;e<8;++e) v[e] = f2bf(ar[e]);
        } else {
          v = *(const u16x8*)((const u16*)Av + (size_t)row*K + k0);
        }
      }
      af[mi] = __builtin_bit_cast(bf16x8, v);
    }
    #pragma unroll
    for(int nt=0; nt<4; ++nt){
      int col = bn + nt*16 + lr;
      const float* wr = W + (size_t)col*K + k0;
      u16x8 wv;
      #pragma unroll
      for(int e=0;e<8;++e) wv[e] = f2bf(wr[e]);
      bf16x8 bfr = __builtin_bit_cast(bf16x8, wv);
      acc[0][nt] = __builtin_amdgcn_mfma_f32_16x16x32_bf16(af[0], bfr, acc[0][nt], 0,0,0);
      acc[1][nt] = __builtin_amdgcn_mfma_f32_16x16x32_bf16(af[1], bfr, acc[1][nt], 0,0,0);
    }
  }
  #pragma unroll
  for(int mi=0; mi<2; ++mi){
    #pragma unroll
    for(int nt=0; nt<4; ++nt){
      int col = bn + nt*16 + lr;
      float bc = bias[col];
      #pragma unroll
      for(int r=0; r<4; ++r){
        int row = bm + mi*16 + lg*4 + r;
        if(row >= M) continue;
        float v = acc[mi][nt][r] + bc;
        if(lens){ int b = row/NTT; int t = row - b*NTT; if(t >= lens[b]) v = bc; }
        if constexpr(OUTF32) ((float*)out)[(size_t)row*N + col] = v;
        else                 ((u16*) out)[(size_t)row*N + col] = f2bf(v);
      }
    }
  }
}

// ---------------- GATv2 attention + aggregate + bias + ELU ----------------
// one wave per destination node; lane l owns dims 2l,2l+1 (head = l>>4)
// xl/xr internal bf16; weights f32; out f32
__global__ __launch_bounds__(256) void k_attn(
    const int* __restrict__ off, const int* __restrict__ csrs, const float* __restrict__ csrw,
    const u16* __restrict__ xl, const u16* __restrict__ xr,
    const float* __restrict__ We, const float* __restrict__ att, const float* __restrict__ bias,
    float* __restrict__ hout)
{
  int wid = threadIdx.x >> 6, l = threadIdx.x & 63;
  int n = blockIdx.x*4 + wid;
  int d0 = 2*l;
  const unsigned int* xl2 = (const unsigned int*)xl;
  unsigned int xru = ((const unsigned int*)xr)[n*64 + l];
  float xrx = bf2f((u16)xru), xry = bf2f((u16)(xru>>16));
  float wex = We[d0],  wey = We[d0+1];
  float atx = att[d0], aty = att[d0+1];
  int p0 = off[n], p1 = off[n+1];
  float mx = -1e30f;
  for(int p=p0; p<p1; ++p){
    int s = csrs[p]; float w = csrw[p];
    unsigned int u = xl2[s*64 + l];
    float ax = bf2f((u16)u)       + xrx + w*wex;
    float ay = bf2f((u16)(u>>16)) + xry + w*wey;
    ax = ax > 0.f ? ax : 0.2f*ax;
    ay = ay > 0.f ? ay : 0.2f*ay;
    float c = ax*atx + ay*aty;
    c += __shfl_xor(c,1); c += __shfl_xor(c,2); c += __shfl_xor(c,4); c += __shfl_xor(c,8);
    mx = fmaxf(mx, c);
  }
  float den = 0.f, a0 = 0.f, a1 = 0.f;
  for(int p=p0; p<p1; ++p){
    int s = csrs[p]; float w = csrw[p];
    unsigned int u = xl2[s*64 + l];
    float xlx = bf2f((u16)u), xly = bf2f((u16)(u>>16));
    float ax = xlx + xrx + w*wex;
    float ay = xly + xry + w*wey;
    ax = ax > 0.f ? ax : 0.2f*ax;
    ay = ay > 0.f ? ay : 0.2f*ay;
    float c = ax*atx + ay*aty;
    c += __shfl_xor(c,1); c += __shfl_xor(c,2); c += __shfl_xor(c,4); c += __shfl_xor(c,8);
    float al = __expf(c - mx);
    den += al; a0 += al*xlx; a1 += al*xly;
  }
  float inv = 1.f/(den + 1e-16f);
  float o0 = a0*inv + bias[d0];
  float o1 = a1*inv + bias[d0+1];
  o0 = o0 > 0.f ? o0 : (__expf(o0) - 1.f);   // ELU
  o1 = o1 > 0.f ? o1 : (__expf(o1) - 1.f);
  hout[n*EMB + d0]   = o0;
  hout[n*EMB + d0+1] = o1;
}

// ---------------- GRU chunk: 16 blocks x 16 batch rows, 8 waves ----------------
// wave w owns 96 Whh rows: gate g in {r,z,n}, j = g*256 + w*32 + jt*16 + lr (jt=0,1).
// f32 state carried across chunks via hsave; h round-trips bf16 via swizzled lds_h.
__global__ __launch_bounds__(512,1) void k_gru(
    const u16* __restrict__ xgc, const float* __restrict__ Whh, const float* __restrict__ bhh,
    const int* __restrict__ lens, u16* __restrict__ hseq, float* __restrict__ hsave,
    int t0, int t1, int chk)
{
  int tid = threadIdx.x;
  int wid = tid >> 6, l = tid & 63;
  int lr = l & 15, lg = l >> 4;
  int b0 = blockIdx.x*16;
  __shared__ u16 lds_h[16*RH];     // 8 KB
  __shared__ u16 lds_xg[16*G3];    // 24 KB

  int maxlen = 0;
  for(int i=0;i<16;++i){ int v = lens[b0+i]; maxlen = v>maxlen ? v : maxlen; }
  int tend = maxlen < t1 ? maxlen : t1;

  // Whh B-fragments (f32 -> bf16), register-resident (192 VGPR)
  bf16x8 wf[6][8];
  float  bh[6];
  #pragma unroll
  for(int nt=0; nt<6; ++nt){
    int g = nt>>1, jt = nt&1;
    int nrow = g*256 + wid*32 + jt*16 + lr;
    bh[nt] = bhh[nrow];
    const float* wr = Whh + (size_t)nrow*RH;
    #pragma unroll
    for(int kt=0; kt<8; ++kt){
      u16x8 wv;
      #pragma unroll
      for(int e=0;e<8;++e) wv[e] = f2bf(wr[kt*32 + lg*8 + e]);
      wf[nt][kt] = __builtin_bit_cast(bf16x8, wv);
    }
  }

  // h init (swizzled lds_h: physical granule c of row holds logical granule c^row)
  {
    int row = tid>>5, cl = tid&31, cg = cl^row;
    u16x8 v = {0,0,0,0,0,0,0,0};
    if(t0 > 0){
      const float* hp = hsave + (size_t)(b0+row)*RH + cg*8;
      #pragma unroll
      for(int e=0;e<8;++e) v[e] = f2bf(hp[e]);
    }
    *(u16x8*)(lds_h + tid*8) = v;
  }
  float hst[8];
  #pragma unroll
  for(int jt=0;jt<2;++jt)
    #pragma unroll
    for(int r=0;r<4;++r){
      int j = wid*32 + jt*16 + lr, row = lg*4 + r;
      hst[jt*4+r] = (t0>0) ? hsave[(size_t)(b0+row)*RH + j] : 0.f;
    }
  int orow = tid>>5, ocl = tid&31, ocg = ocl^orow;
  int mylen = lens[b0 + orow];
  __syncthreads();

  for(int t=t0; t<tend; ++t){
    // prefetch xg(t): pre-swizzled source, linear LDS dest
    u16x8 xv[3];
    #pragma unroll
    for(int it=0; it<3; ++it){
      int ppos = it*512 + tid;                 // 1536 granules = 16 rows x 96
      int row = ppos/96;
      int cg  = (ppos - row*96) ^ row;
      xv[it] = *(const u16x8*)(xgc + ((size_t)((b0+row)*chk + (t - t0)))*G3 + cg*8);
    }
    // hg = h @ Whh^T
    f32x4 acc[6] = {};
    #pragma unroll
    for(int kt=0; kt<8; ++kt){
      int kg = (kt*4 + lg) ^ lr;
      bf16x8 af = __builtin_bit_cast(bf16x8, *(const u16x8*)(lds_h + lr*RH + kg*8));
      #pragma unroll
      for(int nt=0; nt<6; ++nt)
        acc[nt] = __builtin_amdgcn_mfma_f32_16x16x32_bf16(af, wf[nt][kt], acc[nt], 0,0,0);
    }
    #pragma unroll
    for(int it=0; it<3; ++it)
      *(u16x8*)(lds_xg + (it*512 + tid)*8) = xv[it];
    __syncthreads();

    // gates: lane holds C rows (lg*4+r), hidden j = wid*32 + jt*16 + lr
    #pragma unroll
    for(int jt=0; jt<2; ++jt){
      #pragma unroll
      for(int r=0; r<4; ++r){
        int row = lg*4 + r;
        int jl  = wid*32 + jt*16 + lr;
        int jgr = jl>>3, jo = jl&7;
        const u16* xrow = lds_xg + row*G3;
        float xrv = bf2f(xrow[((jgr      )^row)*8 + jo]);
        float xzv = bf2f(xrow[((jgr + 32 )^row)*8 + jo]);
        float xnv = bf2f(xrow[((jgr + 64 )^row)*8 + jo]);
        float hr = acc[0+jt][r] + bh[0+jt];
        float hz = acc[2+jt][r] + bh[2+jt];
        float hn = acc[4+jt][r] + bh[4+jt];
        float rg = 1.f/(1.f + __expf(-(xrv + hr)));
        float zg = 1.f/(1.f + __expf(-(xzv + hz)));
        float nn = xnv + rg*hn;
        float tg = 1.f - 2.f/(__expf(2.f*nn) + 1.f);   // tanh
        float hv = (1.f - zg)*tg + zg*hst[jt*4+r];
        hst[jt*4+r] = hv;
        lds_h[row*RH + ((jl>>3)^row)*8 + jo] = f2bf(hv);
      }
    }
    __syncthreads();

    // copy-out h(t) -> hseq (zeros for t >= len[row], matching pad_packed zeroing)
    {
      u16x8 v = {0,0,0,0,0,0,0,0};
      if(t < mylen) v = *(const u16x8*)(lds_h + tid*8);
      *(u16x8*)(hseq + ((size_t)((b0+orow)*NTT + t))*RH + ocg*8) = v;
    }
  }

  // zero-fill [max(tend,t0), t1) so hseq is fully written & deterministic
  for(int t = (tend > t0 ? tend : t0); t < t1; ++t){
    u16x8 z = {0,0,0,0,0,0,0,0};
    *(u16x8*)(hseq + ((size_t)((b0+orow)*NTT + t))*RH + ocg*8) = z;
  }

  // save exact f32 state for next chunk
  #pragma unroll
  for(int jt=0;jt<2;++jt)
    #pragma unroll
    for(int r=0;r<4;++r){
      int j = wid*32 + jt*16 + lr, row = lg*4 + r;
      hsave[(size_t)(b0+row)*RH + j] = hst[jt*4+r];
    }
}

// ---------------- launcher ----------------
extern "C" void kernel_launch(void* const* d_in, const int* in_sizes, int n_in,
                              void* d_out, int out_size, void* d_ws, size_t ws_size,
                              hipStream_t stream){
  (void)in_sizes; (void)n_in; (void)out_size;
  const int*   skills = (const int*)d_in[0];
  const int*   resp   = (const int*)d_in[1];
  const int*   lens   = (const int*)d_in[2];
  const int*   eidx   = (const int*)d_in[3];
  const float* ew     = (const float*)d_in[4];
  const float* emb    = (const float*)d_in[5];
  const float* gW[2][7];
  for(int l2=0;l2<2;++l2) for(int j=0;j<7;++j) gW[l2][j] = (const float*)d_in[6 + l2*7 + j];
  const float* remb  = (const float*)d_in[20];
  const float* Wih   = (const float*)d_in[21];
  const float* Whh   = (const float*)d_in[22];
  const float* bih   = (const float*)d_in[23];
  const float* bhh   = (const float*)d_in[24];
  const float* projW = (const float*)d_in[25];
  const float* projb = (const float*)d_in[26];

  char* p = (char*)d_ws;
  size_t o = 0;
  auto take = [&](size_t bytes)->char*{ char* r = p + o; o = (o + bytes + 255) & ~(size_t)255; return r; };
  int*   deg  = (int*)  take(4*N_NODES);
  int*   fill = (int*)  take(4*N_NODES);
  float* wsum = (float*)take(4*N_NODES);
  size_t zbytes = o;                        // deg+fill+wsum zeroed each call
  int*   off   = (int*)  take(4*(N_NODES+1));
  int*   csrs  = (int*)  take(4*NE_TOT);
  float* csrw  = (float*)take(4*NE_TOT);
  u16*   xl    = (u16*)  take(2UL*N_NODES*EMB);
  u16*   xr    = (u16*)  take(2UL*N_NODES*EMB);
  float* h1    = (float*)take(4UL*N_NODES*EMB);
  float* hsave = (float*)take(4UL*NB*RH);
  u16*   hseq  = (u16*)  take(2UL*NB*NTT*RH);
  size_t fixed_end = o;
  // xg chunk length: largest of {200,100,50,25} that fits ws_size
  int chk = 200;
  while(chk > 25 && fixed_end + 2UL*NB*(size_t)chk*G3 > ws_size) chk /= 2;
  u16*   xgc  = (u16*)  take(2UL*NB*(size_t)chk*G3);

  float* outP = (float*)d_out;                     // h_proj [256,200,128] f32
  float* outE = outP + (size_t)NB*NTT*EMB;         // skill_embs [10000,128] f32

  hipMemsetAsync(d_ws, 0, zbytes, stream);
  k_deg<<<(NE+255)/256, 256, 0, stream>>>(eidx, ew, deg, wsum);
  k_scan<<<1, 1024, 0, stream>>>(deg, wsum, off);
  k_scatter<<<(NE_TOT+255)/256, 256, 0, stream>>>(eidx, ew, wsum, off, fill, csrs, csrw);

  dim3 gN((N_NODES+127)/128, EMB/64);
  // layer 0 (A = emb f32 -> xl/xr bf16)
  k_gemm<0,false><<<gN, 256, 0, stream>>>(emb, gW[0][0], gW[0][1], xl, N_NODES, EMB, EMB,
                                 nullptr, nullptr, nullptr, 0,0, nullptr);
  k_gemm<0,false><<<gN, 256, 0, stream>>>(emb, gW[0][2], gW[0][3], xr, N_NODES, EMB, EMB,
                                 nullptr, nullptr, nullptr, 0,0, nullptr);
  k_attn<<<N_NODES/4, 256, 0, stream>>>(off, csrs, csrw, xl, xr, gW[0][4], gW[0][5], gW[0][6], h1);
  // layer 1 (A = h1 f32)
  k_gemm<0,false><<<gN, 256, 0, stream>>>(h1, gW[1][0], gW[1][1], xl, N_NODES, EMB, EMB,
                                 nullptr, nullptr, nullptr, 0,0, nullptr);
  k_gemm<0,false><<<gN, 256, 0, stream>>>(h1, gW[1][2], gW[1][3], xr, N_NODES, EMB, EMB,
                                 nullptr, nullptr, nullptr, 0,0, nullptr);
  k_attn<<<N_NODES/4, 256, 0, stream>>>(off, csrs, csrw, xl, xr, gW[1][4], gW[1][5], gW[1][6], outE);

  // chunked: xg = (skill_embs[skills]+resp_emb[resp]) @ Wih^T + bih, then GRU chunk
  for(int t0=0; t0<NTT; t0+=chk){
    k_gemm<1,false><<<dim3(NB*chk/128, G3/64), 256, 0, stream>>>(outE, Wih, bih, xgc,
                                 NB*chk, G3, EMB, skills, resp, remb, t0, chk, nullptr);
    k_gru<<<16, 512, 0, stream>>>(xgc, Whh, bhh, lens, hseq, hsave, t0, t0+chk, chk);
  }
  // proj: A = hseq bf16, out f32 (+ lens mask; hseq rows t>=len are exact zeros)
  k_gemm<2,true><<<dim3(NB*NTT/128, EMB/64), 256, 0, stream>>>(hseq, projW, projb, outP,
                                 NB*NTT, EMB, RH,
                                 nullptr, nullptr, nullptr, 0,0, lens);
}

// Round 5
// 1655.907 us; speedup vs baseline: 1.1053x; 1.1053x over previous
//
#include <hip/hip_runtime.h>

#define N_NODES 10000
#define EMB     128
#define NE      320000
#define NE_TOT  330000   // + one self-loop per node
#define NB      256
#define NTT     200
#define RH      256
#define G3      768

typedef unsigned short u16;
typedef u16    u16x8  __attribute__((ext_vector_type(8)));
typedef __bf16 bf16x8 __attribute__((ext_vector_type(8)));
typedef float  f32x4  __attribute__((ext_vector_type(4)));

static __device__ __forceinline__ float bf2f(u16 u){
  unsigned int x = ((unsigned int)u) << 16;
  return __builtin_bit_cast(float, x);
}
static __device__ __forceinline__ u16 f2bf(float f){
  unsigned int x = __builtin_bit_cast(unsigned int, f);
  x += 0x7fffu + ((x >> 16) & 1u);
  return (u16)(x >> 16);
}

// async global->LDS, 16B per lane; lds dest must be the WAVE base (HW adds lane*16)
static __device__ __forceinline__ void stage16(const u16* g, u16* lds_wavebase, u16* lds_lane){
#if __has_builtin(__builtin_amdgcn_global_load_lds)
  __builtin_amdgcn_global_load_lds(
      (const __attribute__((address_space(1))) unsigned int*)g,
      (__attribute__((address_space(3))) unsigned int*)lds_wavebase, 16, 0, 0);
  (void)lds_lane;
#else
  *(u16x8*)lds_lane = *(const u16x8*)g;
#endif
}

// ---------------- CSR build ----------------
__global__ void k_deg(const int* __restrict__ eidx, const float* __restrict__ ew,
                      int* __restrict__ deg, float* __restrict__ wsum){
  int i = blockIdx.x*256 + threadIdx.x;
  if(i >= NE) return;
  int d = eidx[NE + i];
  atomicAdd(&deg[d], 1);
  atomicAdd(&wsum[d], ew[i]);
}

__global__ __launch_bounds__(1024) void k_scan(const int* __restrict__ deg,
                      float* __restrict__ wsum, int* __restrict__ off){
  __shared__ int part[1024];
  int tid = threadIdx.x;
  int n0 = tid*10;
  int s = 0;
  for(int i=0;i<10;++i){ int n=n0+i; if(n<N_NODES) s += deg[n]+1; }
  part[tid] = s;
  for(int i=0;i<10;++i){
    int n=n0+i;
    if(n<N_NODES){ int d=deg[n]; wsum[n] = wsum[n] / (float)(d>1?d:1); }
  }
  __syncthreads();
  for(int st=1; st<1024; st<<=1){
    int v = (tid>=st) ? part[tid-st] : 0;
    __syncthreads();
    part[tid] += v;
    __syncthreads();
  }
  int base = tid ? part[tid-1] : 0;
  for(int i=0;i<10;++i){ int n=n0+i; if(n<N_NODES){ off[n]=base; base += deg[n]+1; } }
  if(tid==999) off[N_NODES] = base;
}

__global__ void k_scatter(const int* __restrict__ eidx, const float* __restrict__ ew,
                          const float* __restrict__ la, const int* __restrict__ off,
                          int* __restrict__ fill, int* __restrict__ csrs, float* __restrict__ csrw){
  int i = blockIdx.x*256 + threadIdx.x;
  if(i >= NE_TOT) return;
  int s, d; float w;
  if(i < NE){ s = eidx[i]; d = eidx[NE+i]; w = ew[i]; }
  else      { int n = i-NE; s=n; d=n; w = la[n]; }   // self-loop, weight = mean incoming
  int pos = off[d] + atomicAdd(&fill[d], 1);
  csrs[pos] = s; csrw[pos] = w;
}

// ---------------- MFMA GEMM: C = A @ W^T + bias ----------------
// AMODE: 0 = A f32 [M,K]; 1 = gather f32 (A[gidx]+remb[ridx], chunked rows);
//        2 = A bf16 [M,K].
// W: f32 [N,K] (torch Linear). OUTF32: write f32, else bf16.
// lens != null (proj): row=(b*NTT+t), t>=lens[b] -> bias only.
template<int AMODE, bool OUTF32>
__global__ __launch_bounds__(256) void k_gemm(
    const void* __restrict__ Av, const float* __restrict__ W, const float* __restrict__ bias,
    void* __restrict__ out,
    int M, int N, int K,
    const int* __restrict__ gidx, const int* __restrict__ ridx, const float* __restrict__ remb,
    int t0, int chk,
    const int* __restrict__ lens)
{
  int tid = threadIdx.x;
  int wid = tid >> 6, l = tid & 63;
  int lr = l & 15, lg = l >> 4;
  int bm = blockIdx.x*128 + wid*32;
  int bn = blockIdx.y*64;
  f32x4 acc[2][4] = {};
  int nk = K >> 5;
  for(int kt=0; kt<nk; ++kt){
    int k0 = kt*32 + lg*8;
    bf16x8 af[2];
    #pragma unroll
    for(int mi=0; mi<2; ++mi){
      int row = bm + mi*16 + lr;
      u16x8 v = {0,0,0,0,0,0,0,0};
      if(row < M){
        if constexpr(AMODE == 1){
          int b = row / chk, tt = row - b*chk;
          int gi = b*NTT + t0 + tt;
          const float* ar = (const float*)Av + (size_t)gidx[gi]*K + k0;
          const float* rr = remb + (size_t)ridx[gi]*K + k0;
          #pragma unroll
          for(int e=0;e<8;++e) v[e] = f2bf(ar[e] + rr[e]);
        } else if constexpr(AMODE == 0){
          const float* ar = (const float*)Av + (size_t)row*K + k0;
          #pragma unroll
          for(int e=0;e<8;++e) v[e] = f2bf(ar[e]);
        } else {
          v = *(const u16x8*)((const u16*)Av + (size_t)row*K + k0);
        }
      }
      af[mi] = __builtin_bit_cast(bf16x8, v);
    }
    #pragma unroll
    for(int nt=0; nt<4; ++nt){
      int col = bn + nt*16 + lr;
      const float* wr = W + (size_t)col*K + k0;
      u16x8 wv;
      #pragma unroll
      for(int e=0;e<8;++e) wv[e] = f2bf(wr[e]);
      bf16x8 bfr = __builtin_bit_cast(bf16x8, wv);
      acc[0][nt] = __builtin_amdgcn_mfma_f32_16x16x32_bf16(af[0], bfr, acc[0][nt], 0,0,0);
      acc[1][nt] = __builtin_amdgcn_mfma_f32_16x16x32_bf16(af[1], bfr, acc[1][nt], 0,0,0);
    }
  }
  #pragma unroll
  for(int mi=0; mi<2; ++mi){
    #pragma unroll
    for(int nt=0; nt<4; ++nt){
      int col = bn + nt*16 + lr;
      float bc = bias[col];
      #pragma unroll
      for(int r=0; r<4; ++r){
        int row = bm + mi*16 + lg*4 + r;
        if(row >= M) continue;
        float v = acc[mi][nt][r] + bc;
        if(lens){ int b = row/NTT; int t = row - b*NTT; if(t >= lens[b]) v = bc; }
        if constexpr(OUTF32) ((float*)out)[(size_t)row*N + col] = v;
        else                 ((u16*) out)[(size_t)row*N + col] = f2bf(v);
      }
    }
  }
}

// ---------------- GATv2 attention + aggregate + bias + ELU ----------------
__global__ __launch_bounds__(256) void k_attn(
    const int* __restrict__ off, const int* __restrict__ csrs, const float* __restrict__ csrw,
    const u16* __restrict__ xl, const u16* __restrict__ xr,
    const float* __restrict__ We, const float* __restrict__ att, const float* __restrict__ bias,
    float* __restrict__ hout)
{
  int wid = threadIdx.x >> 6, l = threadIdx.x & 63;
  int n = blockIdx.x*4 + wid;
  int d0 = 2*l;
  const unsigned int* xl2 = (const unsigned int*)xl;
  unsigned int xru = ((const unsigned int*)xr)[n*64 + l];
  float xrx = bf2f((u16)xru), xry = bf2f((u16)(xru>>16));
  float wex = We[d0],  wey = We[d0+1];
  float atx = att[d0], aty = att[d0+1];
  int p0 = off[n], p1 = off[n+1];
  float mx = -1e30f;
  for(int p=p0; p<p1; ++p){
    int s = csrs[p]; float w = csrw[p];
    unsigned int u = xl2[s*64 + l];
    float ax = bf2f((u16)u)       + xrx + w*wex;
    float ay = bf2f((u16)(u>>16)) + xry + w*wey;
    ax = ax > 0.f ? ax : 0.2f*ax;
    ay = ay > 0.f ? ay : 0.2f*ay;
    float c = ax*atx + ay*aty;
    c += __shfl_xor(c,1); c += __shfl_xor(c,2); c += __shfl_xor(c,4); c += __shfl_xor(c,8);
    mx = fmaxf(mx, c);
  }
  float den = 0.f, a0 = 0.f, a1 = 0.f;
  for(int p=p0; p<p1; ++p){
    int s = csrs[p]; float w = csrw[p];
    unsigned int u = xl2[s*64 + l];
    float xlx = bf2f((u16)u), xly = bf2f((u16)(u>>16));
    float ax = xlx + xrx + w*wex;
    float ay = xly + xry + w*wey;
    ax = ax > 0.f ? ax : 0.2f*ax;
    ay = ay > 0.f ? ay : 0.2f*ay;
    float c = ax*atx + ay*aty;
    c += __shfl_xor(c,1); c += __shfl_xor(c,2); c += __shfl_xor(c,4); c += __shfl_xor(c,8);
    float al = __expf(c - mx);
    den += al; a0 += al*xlx; a1 += al*xly;
  }
  float inv = 1.f/(den + 1e-16f);
  float o0 = a0*inv + bias[d0];
  float o1 = a1*inv + bias[d0+1];
  o0 = o0 > 0.f ? o0 : (__expf(o0) - 1.f);   // ELU
  o1 = o1 > 0.f ? o1 : (__expf(o1) - 1.f);
  hout[n*EMB + d0]   = o0;
  hout[n*EMB + d0+1] = o1;
}

// ---------------- GRU chunk: 16 blocks x 16 batch rows, 8 waves ----------------
// wave w owns 96 Whh rows: gate g in {r,z,n}, j = g*256 + w*32 + jt*16 + lr (jt=0,1).
// Whh held in 48 NAMED bf16x8 locals (forced SROA -> VGPR-resident, no scratch).
// xg staged via global_load_lds (no staging VGPRs); f32 state across chunks in hsave.

#define DECLW(nt) bf16x8 wf_##nt##_0, wf_##nt##_1, wf_##nt##_2, wf_##nt##_3, \
                         wf_##nt##_4, wf_##nt##_5, wf_##nt##_6, wf_##nt##_7;

#define LDW1(nt,kt) { const float* wp = wr + (kt)*32 + lg*8; u16x8 wv; \
  _Pragma("unroll") for(int e=0;e<8;++e) wv[e]=f2bf(wp[e]); \
  wf_##nt##_##kt = __builtin_bit_cast(bf16x8, wv); }

#define LDW(nt,g,jt) { int nrow = (g)*256 + wid*32 + (jt)*16 + lr; \
  bh[nt] = bhh[nrow]; const float* wr = Whh + (size_t)nrow*RH; \
  LDW1(nt,0) LDW1(nt,1) LDW1(nt,2) LDW1(nt,3) LDW1(nt,4) LDW1(nt,5) LDW1(nt,6) LDW1(nt,7) }

#define MST(kt) { int kg = ((kt)*4 + lg) ^ lr; \
  bf16x8 af = __builtin_bit_cast(bf16x8, *(const u16x8*)(lds_h + lr*RH + kg*8)); \
  acc0 = __builtin_amdgcn_mfma_f32_16x16x32_bf16(af, wf_0_##kt, acc0, 0,0,0); \
  acc1 = __builtin_amdgcn_mfma_f32_16x16x32_bf16(af, wf_1_##kt, acc1, 0,0,0); \
  acc2 = __builtin_amdgcn_mfma_f32_16x16x32_bf16(af, wf_2_##kt, acc2, 0,0,0); \
  acc3 = __builtin_amdgcn_mfma_f32_16x16x32_bf16(af, wf_3_##kt, acc3, 0,0,0); \
  acc4 = __builtin_amdgcn_mfma_f32_16x16x32_bf16(af, wf_4_##kt, acc4, 0,0,0); \
  acc5 = __builtin_amdgcn_mfma_f32_16x16x32_bf16(af, wf_5_##kt, acc5, 0,0,0); }

#define GATES(jt, aR, aZ, aN) { \
  _Pragma("unroll") for(int r=0;r<4;++r){ \
    int row = lg*4 + r; \
    int jl  = wid*32 + (jt)*16 + lr; \
    int jgr = jl>>3, jo = jl&7; \
    const u16* xrow = lds_xg + row*G3; \
    float xrv = bf2f(xrow[((jgr     )^row)*8 + jo]); \
    float xzv = bf2f(xrow[((jgr + 32)^row)*8 + jo]); \
    float xnv = bf2f(xrow[((jgr + 64)^row)*8 + jo]); \
    float hr = aR[r] + bh[0+(jt)]; \
    float hz = aZ[r] + bh[2+(jt)]; \
    float hn = aN[r] + bh[4+(jt)]; \
    float rg = 1.f/(1.f + __expf(-(xrv + hr))); \
    float zg = 1.f/(1.f + __expf(-(xzv + hz))); \
    float nn = xnv + rg*hn; \
    float tg = 1.f - 2.f/(__expf(2.f*nn) + 1.f); \
    float hv = (1.f - zg)*tg + zg*hst[(jt)*4+r]; \
    hst[(jt)*4+r] = hv; \
    lds_h[row*RH + ((jl>>3)^row)*8 + jo] = f2bf(hv); \
  } }

__global__ __launch_bounds__(512,2) void k_gru(
    const u16* __restrict__ xgc, const float* __restrict__ Whh, const float* __restrict__ bhh,
    const int* __restrict__ lens, u16* __restrict__ hseq, float* __restrict__ hsave,
    int t0, int t1, int chk)
{
  int tid = threadIdx.x;
  int wid = tid >> 6, l = tid & 63;
  int lr = l & 15, lg = l >> 4;
  int b0 = blockIdx.x*16;
  __shared__ u16 lds_h[16*RH];     // 8 KB
  __shared__ u16 lds_xg[16*G3];    // 24 KB

  int maxlen = 0;
  for(int i=0;i<16;++i){ int v = lens[b0+i]; maxlen = v>maxlen ? v : maxlen; }
  int tend = maxlen < t1 ? maxlen : t1;

  // Whh B-fragments (f32 -> bf16): 48 named locals, 192 VGPRs
  float bh[6];
  DECLW(0) DECLW(1) DECLW(2) DECLW(3) DECLW(4) DECLW(5)
  LDW(0,0,0) LDW(1,0,1) LDW(2,1,0) LDW(3,1,1) LDW(4,2,0) LDW(5,2,1)

  // h init (swizzled lds_h: physical granule c of row holds logical granule c^row)
  {
    int row = tid>>5, cl = tid&31, cg = cl^row;
    u16x8 v = {0,0,0,0,0,0,0,0};
    if(t0 > 0){
      const float* hp = hsave + (size_t)(b0+row)*RH + cg*8;
      #pragma unroll
      for(int e=0;e<8;++e) v[e] = f2bf(hp[e]);
    }
    *(u16x8*)(lds_h + tid*8) = v;
  }
  float hst[8];
  #pragma unroll
  for(int jt=0;jt<2;++jt)
    #pragma unroll
    for(int r=0;r<4;++r){
      int j = wid*32 + jt*16 + lr, row = lg*4 + r;
      hst[jt*4+r] = (t0>0) ? hsave[(size_t)(b0+row)*RH + j] : 0.f;
    }

  // loop-invariant staging addresses (pre-swizzled global source, linear LDS dest)
  const u16* xsrc0; const u16* xsrc1; const u16* xsrc2;
  {
    int p0s = 0*512 + tid, r0 = p0s/96, c0 = (p0s - r0*96) ^ r0;
    int p1s = 1*512 + tid, r1 = p1s/96, c1 = (p1s - r1*96) ^ r1;
    int p2s = 2*512 + tid, r2 = p2s/96, c2 = (p2s - r2*96) ^ r2;
    xsrc0 = xgc + ((size_t)((b0+r0)*chk))*G3 + c0*8;
    xsrc1 = xgc + ((size_t)((b0+r1)*chk))*G3 + c1*8;
    xsrc2 = xgc + ((size_t)((b0+r2)*chk))*G3 + c2*8;
  }
  u16* lbase0 = lds_xg + (0*512 + wid*64)*8;
  u16* lbase1 = lds_xg + (1*512 + wid*64)*8;
  u16* lbase2 = lds_xg + (2*512 + wid*64)*8;
  u16* llane0 = lds_xg + (0*512 + tid)*8;
  u16* llane1 = lds_xg + (1*512 + tid)*8;
  u16* llane2 = lds_xg + (2*512 + tid)*8;

  int orow = tid>>5, ocl = tid&31, ocg = ocl^orow;
  int mylen = lens[b0 + orow];
  u16* outp = hseq + ((size_t)((b0+orow)*NTT + t0))*RH + ocg*8;
  __syncthreads();

  for(int t=t0; t<tend; ++t){
    // async-stage xg(t) into lds_xg (lands by the next barrier)
    stage16(xsrc0, lbase0, llane0);
    stage16(xsrc1, lbase1, llane1);
    stage16(xsrc2, lbase2, llane2);
    xsrc0 += G3; xsrc1 += G3; xsrc2 += G3;

    // hg = h @ Whh^T  (reads lds_h; weights in registers)
    f32x4 acc0 = {}, acc1 = {}, acc2 = {}, acc3 = {}, acc4 = {}, acc5 = {};
    MST(0) MST(1) MST(2) MST(3) MST(4) MST(5) MST(6) MST(7)

    asm volatile("s_waitcnt vmcnt(0)" ::: "memory");
    __syncthreads();                       // lds_xg ready (all waves), lds_h reads done

    GATES(0, acc0, acc2, acc4)
    GATES(1, acc1, acc3, acc5)
    __syncthreads();                       // lds_h fully written

    // copy-out h(t) -> hseq (zeros for t >= len[row])
    {
      u16x8 v = {0,0,0,0,0,0,0,0};
      if(t < mylen) v = *(const u16x8*)(lds_h + tid*8);
      *(u16x8*)outp = v;
      outp += RH;
    }
  }

  // zero-fill [max(tend,t0), t1) so hseq is fully written & deterministic
  for(int t = (tend > t0 ? tend : t0); t < t1; ++t){
    u16x8 z = {0,0,0,0,0,0,0,0};
    *(u16x8*)outp = z;
    outp += RH;
  }

  // save exact f32 state for next chunk
  #pragma unroll
  for(int jt=0;jt<2;++jt)
    #pragma unroll
    for(int r=0;r<4;++r){
      int j = wid*32 + jt*16 + lr, row = lg*4 + r;
      hsave[(size_t)(b0+row)*RH + j] = hst[jt*4+r];
    }
}

// ---------------- launcher ----------------
extern "C" void kernel_launch(void* const* d_in, const int* in_sizes, int n_in,
                              void* d_out, int out_size, void* d_ws, size_t ws_size,
                              hipStream_t stream){
  (void)in_sizes; (void)n_in; (void)out_size;
  const int*   skills = (const int*)d_in[0];
  const int*   resp   = (const int*)d_in[1];
  const int*   lens   = (const int*)d_in[2];
  const int*   eidx   = (const int*)d_in[3];
  const float* ew     = (const float*)d_in[4];
  const float* emb    = (const float*)d_in[5];
  const float* gW[2][7];
  for(int l2=0;l2<2;++l2) for(int j=0;j<7;++j) gW[l2][j] = (const float*)d_in[6 + l2*7 + j];
  const float* remb  = (const float*)d_in[20];
  const float* Wih   = (const float*)d_in[21];
  const float* Whh   = (const float*)d_in[22];
  const float* bih   = (const float*)d_in[23];
  const float* bhh   = (const float*)d_in[24];
  const float* projW = (const float*)d_in[25];
  const float* projb = (const float*)d_in[26];

  char* p = (char*)d_ws;
  size_t o = 0;
  auto take = [&](size_t bytes)->char*{ char* r = p + o; o = (o + bytes + 255) & ~(size_t)255; return r; };
  int*   deg  = (int*)  take(4*N_NODES);
  int*   fill = (int*)  take(4*N_NODES);
  float* wsum = (float*)take(4*N_NODES);
  size_t zbytes = o;                        // deg+fill+wsum zeroed each call
  int*   off   = (int*)  take(4*(N_NODES+1));
  int*   csrs  = (int*)  take(4*NE_TOT);
  float* csrw  = (float*)take(4*NE_TOT);
  u16*   xl    = (u16*)  take(2UL*N_NODES*EMB);
  u16*   xr    = (u16*)  take(2UL*N_NODES*EMB);
  float* h1    = (float*)take(4UL*N_NODES*EMB);
  float* hsave = (float*)take(4UL*NB*RH);
  u16*   hseq  = (u16*)  take(2UL*NB*NTT*RH);
  size_t fixed_end = o;
  // xg chunk length: largest of {200,100,50,25} that fits ws_size
  int chk = 200;
  while(chk > 25 && fixed_end + 2UL*NB*(size_t)chk*G3 > ws_size) chk /= 2;
  u16*   xgc  = (u16*)  take(2UL*NB*(size_t)chk*G3);

  float* outP = (float*)d_out;                     // h_proj [256,200,128] f32
  float* outE = outP + (size_t)NB*NTT*EMB;         // skill_embs [10000,128] f32

  hipMemsetAsync(d_ws, 0, zbytes, stream);
  k_deg<<<(NE+255)/256, 256, 0, stream>>>(eidx, ew, deg, wsum);
  k_scan<<<1, 1024, 0, stream>>>(deg, wsum, off);
  k_scatter<<<(NE_TOT+255)/256, 256, 0, stream>>>(eidx, ew, wsum, off, fill, csrs, csrw);

  dim3 gN((N_NODES+127)/128, EMB/64);
  // layer 0 (A = emb f32 -> xl/xr bf16)
  k_gemm<0,false><<<gN, 256, 0, stream>>>(emb, gW[0][0], gW[0][1], xl, N_NODES, EMB, EMB,
                                 nullptr, nullptr, nullptr, 0,0, nullptr);
  k_gemm<0,false><<<gN, 256, 0, stream>>>(emb, gW[0][2], gW[0][3], xr, N_NODES, EMB, EMB,
                                 nullptr, nullptr, nullptr, 0,0, nullptr);
  k_attn<<<N_NODES/4, 256, 0, stream>>>(off, csrs, csrw, xl, xr, gW[0][4], gW[0][5], gW[0][6], h1);
  // layer 1 (A = h1 f32)
  k_gemm<0,false><<<gN, 256, 0, stream>>>(h1, gW[1][0], gW[1][1], xl, N_NODES, EMB, EMB,
                                 nullptr, nullptr, nullptr, 0,0, nullptr);
  k_gemm<0,false><<<gN, 256, 0, stream>>>(h1, gW[1][2], gW[1][3], xr, N_NODES, EMB, EMB,
                                 nullptr, nullptr, nullptr, 0,0, nullptr);
  k_attn<<<N_NODES/4, 256, 0, stream>>>(off, csrs, csrw, xl, xr, gW[1][4], gW[1][5], gW[1][6], outE);

  // chunked: xg = (skill_embs[skills]+resp_emb[resp]) @ Wih^T + bih, then GRU chunk
  for(int t0=0; t0<NTT; t0+=chk){
    k_gemm<1,false><<<dim3(NB*chk/128, G3/64), 256, 0, stream>>>(outE, Wih, bih, xgc,
                                 NB*chk, G3, EMB, skills, resp, remb, t0, chk, nullptr);
    k_gru<<<16, 512, 0, stream>>>(xgc, Whh, bhh, lens, hseq, hsave, t0, t0+chk, chk);
  }
  // proj: A = hseq bf16, out f32 (+ lens mask; hseq rows t>=len are exact zeros)
  k_gemm<2,true><<<dim3(NB*NTT/128, EMB/64), 256, 0, stream>>>(hseq, projW, projb, outP,
                                 NB*NTT, EMB, RH,
                                 nullptr, nullptr, nullptr, 0,0, lens);
}

// Round 7
// 1654.209 us; speedup vs baseline: 1.1065x; 1.0010x over previous
//
#include <hip/hip_runtime.h>

#define N_NODES 10000
#define EMB     128
#define NE      320000
#define NE_TOT  330000   // + one self-loop per node
#define NB      256
#define NTT     200
#define RH      256
#define G3      768

typedef unsigned short u16;
typedef u16    u16x8  __attribute__((ext_vector_type(8)));
typedef __bf16 bf16x8 __attribute__((ext_vector_type(8)));
typedef float  f32x4  __attribute__((ext_vector_type(4)));

static __device__ __forceinline__ float bf2f(u16 u){
  unsigned int x = ((unsigned int)u) << 16;
  return __builtin_bit_cast(float, x);
}
static __device__ __forceinline__ u16 f2bf(float f){
  unsigned int x = __builtin_bit_cast(unsigned int, f);
  x += 0x7fffu + ((x >> 16) & 1u);
  return (u16)(x >> 16);
}

// async global->LDS, 16B per lane; lds dest must be the WAVE base (HW adds lane*16)
static __device__ __forceinline__ void stage16(const u16* g, u16* lds_wavebase, u16* lds_lane){
#if __has_builtin(__builtin_amdgcn_global_load_lds)
  __builtin_amdgcn_global_load_lds(
      (const __attribute__((address_space(1))) unsigned int*)g,
      (__attribute__((address_space(3))) unsigned int*)lds_wavebase, 16, 0, 0);
  (void)lds_lane;
#else
  *(u16x8*)lds_lane = *(const u16x8*)g;
#endif
}

// ---------------- CSR build ----------------
__global__ void k_deg(const int* __restrict__ eidx, const float* __restrict__ ew,
                      int* __restrict__ deg, float* __restrict__ wsum){
  int i = blockIdx.x*256 + threadIdx.x;
  if(i >= NE) return;
  int d = eidx[NE + i];
  atomicAdd(&deg[d], 1);
  atomicAdd(&wsum[d], ew[i]);
}

__global__ __launch_bounds__(1024) void k_scan(const int* __restrict__ deg,
                      float* __restrict__ wsum, int* __restrict__ off){
  __shared__ int part[1024];
  int tid = threadIdx.x;
  int n0 = tid*10;
  int s = 0;
  for(int i=0;i<10;++i){ int n=n0+i; if(n<N_NODES) s += deg[n]+1; }
  part[tid] = s;
  for(int i=0;i<10;++i){
    int n=n0+i;
    if(n<N_NODES){ int d=deg[n]; wsum[n] = wsum[n] / (float)(d>1?d:1); }
  }
  __syncthreads();
  for(int st=1; st<1024; st<<=1){
    int v = (tid>=st) ? part[tid-st] : 0;
    __syncthreads();
    part[tid] += v;
    __syncthreads();
  }
  int base = tid ? part[tid-1] : 0;
  for(int i=0;i<10;++i){ int n=n0+i; if(n<N_NODES){ off[n]=base; base += deg[n]+1; } }
  if(tid==999) off[N_NODES] = base;
}

__global__ void k_scatter(const int* __restrict__ eidx, const float* __restrict__ ew,
                          const float* __restrict__ la, const int* __restrict__ off,
                          int* __restrict__ fill, int* __restrict__ csrs, float* __restrict__ csrw){
  int i = blockIdx.x*256 + threadIdx.x;
  if(i >= NE_TOT) return;
  int s, d; float w;
  if(i < NE){ s = eidx[i]; d = eidx[NE+i]; w = ew[i]; }
  else      { int n = i-NE; s=n; d=n; w = la[n]; }   // self-loop, weight = mean incoming
  int pos = off[d] + atomicAdd(&fill[d], 1);
  csrs[pos] = s; csrw[pos] = w;
}

// ---------------- MFMA GEMM: C = A @ W^T + bias ----------------
// AMODE: 0 = A f32 [M,K]; 1 = gather f32 (A[gidx]+remb[ridx], chunked rows);
//        2 = A bf16 [M,K].
// W: f32 [N,K] (torch Linear). OUTF32: write f32, else bf16.
// lens != null (proj): row=(b*NTT+t), t>=lens[b] -> bias only.
template<int AMODE, bool OUTF32>
__global__ __launch_bounds__(256) void k_gemm(
    const void* __restrict__ Av, const float* __restrict__ W, const float* __restrict__ bias,
    void* __restrict__ out,
    int M, int N, int K,
    const int* __restrict__ gidx, const int* __restrict__ ridx, const float* __restrict__ remb,
    int t0, int chk,
    const int* __restrict__ lens)
{
  int tid = threadIdx.x;
  int wid = tid >> 6, l = tid & 63;
  int lr = l & 15, lg = l >> 4;
  int bm = blockIdx.x*128 + wid*32;
  int bn = blockIdx.y*64;
  f32x4 acc[2][4] = {};
  int nk = K >> 5;
  for(int kt=0; kt<nk; ++kt){
    int k0 = kt*32 + lg*8;
    bf16x8 af[2];
    #pragma unroll
    for(int mi=0; mi<2; ++mi){
      int row = bm + mi*16 + lr;
      u16x8 v = {0,0,0,0,0,0,0,0};
      if(row < M){
        if constexpr(AMODE == 1){
          int b = row / chk, tt = row - b*chk;
          int gi = b*NTT + t0 + tt;
          const float* ar = (const float*)Av + (size_t)gidx[gi]*K + k0;
          const float* rr = remb + (size_t)ridx[gi]*K + k0;
          #pragma unroll
          for(int e=0;e<8;++e) v[e] = f2bf(ar[e] + rr[e]);
        } else if constexpr(AMODE == 0){
          const float* ar = (const float*)Av + (size_t)row*K + k0;
          #pragma unroll
          for(int e=0;e<8;++e) v[e] = f2bf(ar[e]);
        } else {
          v = *(const u16x8*)((const u16*)Av + (size_t)row*K + k0);
        }
      }
      af[mi] = __builtin_bit_cast(bf16x8, v);
    }
    #pragma unroll
    for(int nt=0; nt<4; ++nt){
      int col = bn + nt*16 + lr;
      const float* wr = W + (size_t)col*K + k0;
      u16x8 wv;
      #pragma unroll
      for(int e=0;e<8;++e) wv[e] = f2bf(wr[e]);
      bf16x8 bfr = __builtin_bit_cast(bf16x8, wv);
      acc[0][nt] = __builtin_amdgcn_mfma_f32_16x16x32_bf16(af[0], bfr, acc[0][nt], 0,0,0);
      acc[1][nt] = __builtin_amdgcn_mfma_f32_16x16x32_bf16(af[1], bfr, acc[1][nt], 0,0,0);
    }
  }
  #pragma unroll
  for(int mi=0; mi<2; ++mi){
    #pragma unroll
    for(int nt=0; nt<4; ++nt){
      int col = bn + nt*16 + lr;
      float bc = bias[col];
      #pragma unroll
      for(int r=0; r<4; ++r){
        int row = bm + mi*16 + lg*4 + r;
        if(row >= M) continue;
        float v = acc[mi][nt][r] + bc;
        if(lens){ int b = row/NTT; int t = row - b*NTT; if(t >= lens[b]) v = bc; }
        if constexpr(OUTF32) ((float*)out)[(size_t)row*N + col] = v;
        else                 ((u16*) out)[(size_t)row*N + col] = f2bf(v);
      }
    }
  }
}

// ---------------- GATv2 attention + aggregate + bias + ELU ----------------
__global__ __launch_bounds__(256) void k_attn(
    const int* __restrict__ off, const int* __restrict__ csrs, const float* __restrict__ csrw,
    const u16* __restrict__ xl, const u16* __restrict__ xr,
    const float* __restrict__ We, const float* __restrict__ att, const float* __restrict__ bias,
    float* __restrict__ hout)
{
  int wid = threadIdx.x >> 6, l = threadIdx.x & 63;
  int n = blockIdx.x*4 + wid;
  int d0 = 2*l;
  const unsigned int* xl2 = (const unsigned int*)xl;
  unsigned int xru = ((const unsigned int*)xr)[n*64 + l];
  float xrx = bf2f((u16)xru), xry = bf2f((u16)(xru>>16));
  float wex = We[d0],  wey = We[d0+1];
  float atx = att[d0], aty = att[d0+1];
  int p0 = off[n], p1 = off[n+1];
  float mx = -1e30f;
  for(int p=p0; p<p1; ++p){
    int s = csrs[p]; float w = csrw[p];
    unsigned int u = xl2[s*64 + l];
    float ax = bf2f((u16)u)       + xrx + w*wex;
    float ay = bf2f((u16)(u>>16)) + xry + w*wey;
    ax = ax > 0.f ? ax : 0.2f*ax;
    ay = ay > 0.f ? ay : 0.2f*ay;
    float c = ax*atx + ay*aty;
    c += __shfl_xor(c,1); c += __shfl_xor(c,2); c += __shfl_xor(c,4); c += __shfl_xor(c,8);
    mx = fmaxf(mx, c);
  }
  float den = 0.f, a0 = 0.f, a1 = 0.f;
  for(int p=p0; p<p1; ++p){
    int s = csrs[p]; float w = csrw[p];
    unsigned int u = xl2[s*64 + l];
    float xlx = bf2f((u16)u), xly = bf2f((u16)(u>>16));
    float ax = xlx + xrx + w*wex;
    float ay = xly + xry + w*wey;
    ax = ax > 0.f ? ax : 0.2f*ax;
    ay = ay > 0.f ? ay : 0.2f*ay;
    float c = ax*atx + ay*aty;
    c += __shfl_xor(c,1); c += __shfl_xor(c,2); c += __shfl_xor(c,4); c += __shfl_xor(c,8);
    float al = __expf(c - mx);
    den += al; a0 += al*xlx; a1 += al*xly;
  }
  float inv = 1.f/(den + 1e-16f);
  float o0 = a0*inv + bias[d0];
  float o1 = a1*inv + bias[d0+1];
  o0 = o0 > 0.f ? o0 : (__expf(o0) - 1.f);   // ELU
  o1 = o1 > 0.f ? o1 : (__expf(o1) - 1.f);
  hout[n*EMB + d0]   = o0;
  hout[n*EMB + d0+1] = o1;
}

// ---------------- GRU chunk: 16 blocks x 16 batch rows, 8 waves ----------------
// wave w owns 96 Whh rows: gate g in {r,z,n}, j = g*256 + w*32 + jt*16 + lr (jt=0,1).
// Whh held in 48 named bf16x8 locals; amdgpu_waves_per_eu(2,2) pins the allocator
// to a 256-VGPR budget so the ~250-reg live set stays register-resident (no spill).
// xg staged via global_load_lds; f32 state across chunks in hsave.

#define DECLW(nt) bf16x8 wf_##nt##_0, wf_##nt##_1, wf_##nt##_2, wf_##nt##_3, \
                         wf_##nt##_4, wf_##nt##_5, wf_##nt##_6, wf_##nt##_7;

#define LDW1(nt,kt) { const float* wp = wr + (kt)*32 + lg*8; u16x8 wv; \
  _Pragma("unroll") for(int e=0;e<8;++e) wv[e]=f2bf(wp[e]); \
  wf_##nt##_##kt = __builtin_bit_cast(bf16x8, wv); }

#define LDW(nt,g,jt) { int nrow = (g)*256 + wid*32 + (jt)*16 + lr; \
  bh[nt] = bhh[nrow]; const float* wr = Whh + (size_t)nrow*RH; \
  LDW1(nt,0) LDW1(nt,1) LDW1(nt,2) LDW1(nt,3) LDW1(nt,4) LDW1(nt,5) LDW1(nt,6) LDW1(nt,7) }

#define MST(kt) { int kg = ((kt)*4 + lg) ^ lr; \
  bf16x8 af = __builtin_bit_cast(bf16x8, *(const u16x8*)(lds_h + lr*RH + kg*8)); \
  acc0 = __builtin_amdgcn_mfma_f32_16x16x32_bf16(af, wf_0_##kt, acc0, 0,0,0); \
  acc1 = __builtin_amdgcn_mfma_f32_16x16x32_bf16(af, wf_1_##kt, acc1, 0,0,0); \
  acc2 = __builtin_amdgcn_mfma_f32_16x16x32_bf16(af, wf_2_##kt, acc2, 0,0,0); \
  acc3 = __builtin_amdgcn_mfma_f32_16x16x32_bf16(af, wf_3_##kt, acc3, 0,0,0); \
  acc4 = __builtin_amdgcn_mfma_f32_16x16x32_bf16(af, wf_4_##kt, acc4, 0,0,0); \
  acc5 = __builtin_amdgcn_mfma_f32_16x16x32_bf16(af, wf_5_##kt, acc5, 0,0,0); }

#define GATES(jt, aR, aZ, aN) { \
  _Pragma("unroll") for(int r=0;r<4;++r){ \
    int row = lg*4 + r; \
    int jl  = wid*32 + (jt)*16 + lr; \
    int jgr = jl>>3, jo = jl&7; \
    const u16* xrow = lds_xg + row*G3; \
    float xrv = bf2f(xrow[((jgr     )^row)*8 + jo]); \
    float xzv = bf2f(xrow[((jgr + 32)^row)*8 + jo]); \
    float xnv = bf2f(xrow[((jgr + 64)^row)*8 + jo]); \
    float hr = aR[r] + bh[0+(jt)]; \
    float hz = aZ[r] + bh[2+(jt)]; \
    float hn = aN[r] + bh[4+(jt)]; \
    float rg = 1.f/(1.f + __expf(-(xrv + hr))); \
    float zg = 1.f/(1.f + __expf(-(xzv + hz))); \
    float nn = xnv + rg*hn; \
    float tg = 1.f - 2.f/(__expf(2.f*nn) + 1.f); \
    float hv = (1.f - zg)*tg + zg*hst[(jt)*4+r]; \
    hst[(jt)*4+r] = hv; \
    lds_h[row*RH + ((jl>>3)^row)*8 + jo] = f2bf(hv); \
  } }

__global__ __launch_bounds__(512) __attribute__((amdgpu_waves_per_eu(2,2))) void k_gru(
    const u16* __restrict__ xgc, const float* __restrict__ Whh, const float* __restrict__ bhh,
    const int* __restrict__ lens, u16* __restrict__ hseq, float* __restrict__ hsave,
    int t0, int t1, int chk)
{
  int tid = threadIdx.x;
  int wid = tid >> 6, l = tid & 63;
  int lr = l & 15, lg = l >> 4;
  int b0 = blockIdx.x*16;
  __shared__ u16 lds_h[16*RH];     // 8 KB
  __shared__ u16 lds_xg[16*G3];    // 24 KB

  int maxlen = 0;
  for(int i=0;i<16;++i){ int v = lens[b0+i]; maxlen = v>maxlen ? v : maxlen; }
  int tend = maxlen < t1 ? maxlen : t1;

  // Whh B-fragments (f32 -> bf16): 48 named locals, 192 VGPRs
  float bh[6];
  DECLW(0) DECLW(1) DECLW(2) DECLW(3) DECLW(4) DECLW(5)
  LDW(0,0,0) LDW(1,0,1) LDW(2,1,0) LDW(3,1,1) LDW(4,2,0) LDW(5,2,1)

  // h init (swizzled lds_h: physical granule c of row holds logical granule c^row)
  {
    int row = tid>>5, cl = tid&31, cg = cl^row;
    u16x8 v = {0,0,0,0,0,0,0,0};
    if(t0 > 0){
      const float* hp = hsave + (size_t)(b0+row)*RH + cg*8;
      #pragma unroll
      for(int e=0;e<8;++e) v[e] = f2bf(hp[e]);
    }
    *(u16x8*)(lds_h + tid*8) = v;
  }
  float hst[8];
  #pragma unroll
  for(int jt=0;jt<2;++jt)
    #pragma unroll
    for(int r=0;r<4;++r){
      int j = wid*32 + jt*16 + lr, row = lg*4 + r;
      hst[jt*4+r] = (t0>0) ? hsave[(size_t)(b0+row)*RH + j] : 0.f;
    }

  // loop-invariant staging addresses (pre-swizzled global source, linear LDS dest)
  const u16* xsrc0; const u16* xsrc1; const u16* xsrc2;
  {
    int p0s = 0*512 + tid, r0 = p0s/96, c0 = (p0s - r0*96) ^ r0;
    int p1s = 1*512 + tid, r1 = p1s/96, c1 = (p1s - r1*96) ^ r1;
    int p2s = 2*512 + tid, r2 = p2s/96, c2 = (p2s - r2*96) ^ r2;
    xsrc0 = xgc + ((size_t)((b0+r0)*chk))*G3 + c0*8;
    xsrc1 = xgc + ((size_t)((b0+r1)*chk))*G3 + c1*8;
    xsrc2 = xgc + ((size_t)((b0+r2)*chk))*G3 + c2*8;
  }
  u16* lbase0 = lds_xg + (0*512 + wid*64)*8;
  u16* lbase1 = lds_xg + (1*512 + wid*64)*8;
  u16* lbase2 = lds_xg + (2*512 + wid*64)*8;
  u16* llane0 = lds_xg + (0*512 + tid)*8;
  u16* llane1 = lds_xg + (1*512 + tid)*8;
  u16* llane2 = lds_xg + (2*512 + tid)*8;

  int orow = tid>>5, ocl = tid&31, ocg = ocl^orow;
  int mylen = lens[b0 + orow];
  u16* outp = hseq + ((size_t)((b0+orow)*NTT + t0))*RH + ocg*8;
  __syncthreads();

  for(int t=t0; t<tend; ++t){
    // async-stage xg(t) into lds_xg (lands by the next barrier)
    stage16(xsrc0, lbase0, llane0);
    stage16(xsrc1, lbase1, llane1);
    stage16(xsrc2, lbase2, llane2);
    xsrc0 += G3; xsrc1 += G3; xsrc2 += G3;

    // hg = h @ Whh^T  (reads lds_h; weights in registers)
    f32x4 acc0 = {}, acc1 = {}, acc2 = {}, acc3 = {}, acc4 = {}, acc5 = {};
    MST(0) MST(1) MST(2) MST(3) MST(4) MST(5) MST(6) MST(7)

    asm volatile("s_waitcnt vmcnt(0)" ::: "memory");
    __syncthreads();                       // lds_xg ready (all waves), lds_h reads done

    GATES(0, acc0, acc2, acc4)
    GATES(1, acc1, acc3, acc5)
    __syncthreads();                       // lds_h fully written

    // copy-out h(t) -> hseq (zeros for t >= len[row])
    {
      u16x8 v = {0,0,0,0,0,0,0,0};
      if(t < mylen) v = *(const u16x8*)(lds_h + tid*8);
      *(u16x8*)outp = v;
      outp += RH;
    }
  }

  // zero-fill [max(tend,t0), t1) so hseq is fully written & deterministic
  for(int t = (tend > t0 ? tend : t0); t < t1; ++t){
    u16x8 z = {0,0,0,0,0,0,0,0};
    *(u16x8*)outp = z;
    outp += RH;
  }

  // save exact f32 state for next chunk
  #pragma unroll
  for(int jt=0;jt<2;++jt)
    #pragma unroll
    for(int r=0;r<4;++r){
      int j = wid*32 + jt*16 + lr, row = lg*4 + r;
      hsave[(size_t)(b0+row)*RH + j] = hst[jt*4+r];
    }
}

// ---------------- launcher ----------------
extern "C" void kernel_launch(void* const* d_in, const int* in_sizes, int n_in,
                              void* d_out, int out_size, void* d_ws, size_t ws_size,
                              hipStream_t stream){
  (void)in_sizes; (void)n_in; (void)out_size;
  const int*   skills = (const int*)d_in[0];
  const int*   resp   = (const int*)d_in[1];
  const int*   lens   = (const int*)d_in[2];
  const int*   eidx   = (const int*)d_in[3];
  const float* ew     = (const float*)d_in[4];
  const float* emb    = (const float*)d_in[5];
  const float* gW[2][7];
  for(int l2=0;l2<2;++l2) for(int j=0;j<7;++j) gW[l2][j] = (const float*)d_in[6 + l2*7 + j];
  const float* remb  = (const float*)d_in[20];
  const float* Wih   = (const float*)d_in[21];
  const float* Whh   = (const float*)d_in[22];
  const float* bih   = (const float*)d_in[23];
  const float* bhh   = (const float*)d_in[24];
  const float* projW = (const float*)d_in[25];
  const float* projb = (const float*)d_in[26];

  char* p = (char*)d_ws;
  size_t o = 0;
  auto take = [&](size_t bytes)->char*{ char* r = p + o; o = (o + bytes + 255) & ~(size_t)255; return r; };
  int*   deg  = (int*)  take(4*N_NODES);
  int*   fill = (int*)  take(4*N_NODES);
  float* wsum = (float*)take(4*N_NODES);
  size_t zbytes = o;                        // deg+fill+wsum zeroed each call
  int*   off   = (int*)  take(4*(N_NODES+1));
  int*   csrs  = (int*)  take(4*NE_TOT);
  float* csrw  = (float*)take(4*NE_TOT);
  u16*   xl    = (u16*)  take(2UL*N_NODES*EMB);
  u16*   xr    = (u16*)  take(2UL*N_NODES*EMB);
  float* h1    = (float*)take(4UL*N_NODES*EMB);
  float* hsave = (float*)take(4UL*NB*RH);
  u16*   hseq  = (u16*)  take(2UL*NB*NTT*RH);
  size_t fixed_end = o;
  // xg chunk length: largest of {200,100,50,25} that fits ws_size
  int chk = 200;
  while(chk > 25 && fixed_end + 2UL*NB*(size_t)chk*G3 > ws_size) chk /= 2;
  u16*   xgc  = (u16*)  take(2UL*NB*(size_t)chk*G3);

  float* outP = (float*)d_out;                     // h_proj [256,200,128] f32
  float* outE = outP + (size_t)NB*NTT*EMB;         // skill_embs [10000,128] f32

  hipMemsetAsync(d_ws, 0, zbytes, stream);
  k_deg<<<(NE+255)/256, 256, 0, stream>>>(eidx, ew, deg, wsum);
  k_scan<<<1, 1024, 0, stream>>>(deg, wsum, off);
  k_scatter<<<(NE_TOT+255)/256, 256, 0, stream>>>(eidx, ew, wsum, off, fill, csrs, csrw);

  dim3 gN((N_NODES+127)/128, EMB/64);
  // layer 0 (A = emb f32 -> xl/xr bf16)
  k_gemm<0,false><<<gN, 256, 0, stream>>>(emb, gW[0][0], gW[0][1], xl, N_NODES, EMB, EMB,
                                 nullptr, nullptr, nullptr, 0,0, nullptr);
  k_gemm<0,false><<<gN, 256, 0, stream>>>(emb, gW[0][2], gW[0][3], xr, N_NODES, EMB, EMB,
                                 nullptr, nullptr, nullptr, 0,0, nullptr);
  k_attn<<<N_NODES/4, 256, 0, stream>>>(off, csrs, csrw, xl, xr, gW[0][4], gW[0][5], gW[0][6], h1);
  // layer 1 (A = h1 f32)
  k_gemm<0,false><<<gN, 256, 0, stream>>>(h1, gW[1][0], gW[1][1], xl, N_NODES, EMB, EMB,
                                 nullptr, nullptr, nullptr, 0,0, nullptr);
  k_gemm<0,false><<<gN, 256, 0, stream>>>(h1, gW[1][2], gW[1][3], xr, N_NODES, EMB, EMB,
                                 nullptr, nullptr, nullptr, 0,0, nullptr);
  k_attn<<<N_NODES/4, 256, 0, stream>>>(off, csrs, csrw, xl, xr, gW[1][4], gW[1][5], gW[1][6], outE);

  // chunked: xg = (skill_embs[skills]+resp_emb[resp]) @ Wih^T + bih, then GRU chunk
  for(int t0=0; t0<NTT; t0+=chk){
    k_gemm<1,false><<<dim3(NB*chk/128, G3/64), 256, 0, stream>>>(outE, Wih, bih, xgc,
                                 NB*chk, G3, EMB, skills, resp, remb, t0, chk, nullptr);
    k_gru<<<16, 512, 0, stream>>>(xgc, Whh, bhh, lens, hseq, hsave, t0, t0+chk, chk);
  }
  // proj: A = hseq bf16, out f32 (+ lens mask; hseq rows t>=len are exact zeros)
  k_gemm<2,true><<<dim3(NB*NTT/128, EMB/64), 256, 0, stream>>>(hseq, projW, projb, outP,
                                 NB*NTT, EMB, RH,
                                 nullptr, nullptr, nullptr, 0,0, lens);
}

// Round 8
// 1624.266 us; speedup vs baseline: 1.1269x; 1.0184x over previous
//
#include <hip/hip_runtime.h>

#define N_NODES 10000
#define EMB     128
#define NE      320000
#define NE_TOT  330000   // + one self-loop per node
#define NB      256
#define NTT     200
#define RH      256
#define G3      768

typedef unsigned short u16;
typedef u16    u16x8  __attribute__((ext_vector_type(8)));
typedef __bf16 bf16x8 __attribute__((ext_vector_type(8)));
typedef float  f32x4  __attribute__((ext_vector_type(4)));

static __device__ __forceinline__ float bf2f(u16 u){
  unsigned int x = ((unsigned int)u) << 16;
  return __builtin_bit_cast(float, x);
}
static __device__ __forceinline__ u16 f2bf(float f){
  unsigned int x = __builtin_bit_cast(unsigned int, f);
  x += 0x7fffu + ((x >> 16) & 1u);
  return (u16)(x >> 16);
}

// opaque register pin: value must be materialized in VGPRs here (anti-sink/remat)
static __device__ __forceinline__ f32x4 keepf(f32x4 v){
  asm volatile("" : "+v"(v));
  return v;
}

// async global->LDS, 16B per lane; lds dest must be the WAVE base (HW adds lane*16)
static __device__ __forceinline__ void stage16(const u16* g, u16* lds_wavebase, u16* lds_lane){
#if __has_builtin(__builtin_amdgcn_global_load_lds)
  __builtin_amdgcn_global_load_lds(
      (const __attribute__((address_space(1))) unsigned int*)g,
      (__attribute__((address_space(3))) unsigned int*)lds_wavebase, 16, 0, 0);
  (void)lds_lane;
#else
  *(u16x8*)lds_lane = *(const u16x8*)g;
#endif
}

// ---------------- CSR build ----------------
__global__ void k_deg(const int* __restrict__ eidx, const float* __restrict__ ew,
                      int* __restrict__ deg, float* __restrict__ wsum){
  int i = blockIdx.x*256 + threadIdx.x;
  if(i >= NE) return;
  int d = eidx[NE + i];
  atomicAdd(&deg[d], 1);
  atomicAdd(&wsum[d], ew[i]);
}

__global__ __launch_bounds__(1024) void k_scan(const int* __restrict__ deg,
                      float* __restrict__ wsum, int* __restrict__ off){
  __shared__ int part[1024];
  int tid = threadIdx.x;
  int n0 = tid*10;
  int s = 0;
  for(int i=0;i<10;++i){ int n=n0+i; if(n<N_NODES) s += deg[n]+1; }
  part[tid] = s;
  for(int i=0;i<10;++i){
    int n=n0+i;
    if(n<N_NODES){ int d=deg[n]; wsum[n] = wsum[n] / (float)(d>1?d:1); }
  }
  __syncthreads();
  for(int st=1; st<1024; st<<=1){
    int v = (tid>=st) ? part[tid-st] : 0;
    __syncthreads();
    part[tid] += v;
    __syncthreads();
  }
  int base = tid ? part[tid-1] : 0;
  for(int i=0;i<10;++i){ int n=n0+i; if(n<N_NODES){ off[n]=base; base += deg[n]+1; } }
  if(tid==999) off[N_NODES] = base;
}

__global__ void k_scatter(const int* __restrict__ eidx, const float* __restrict__ ew,
                          const float* __restrict__ la, const int* __restrict__ off,
                          int* __restrict__ fill, int* __restrict__ csrs, float* __restrict__ csrw){
  int i = blockIdx.x*256 + threadIdx.x;
  if(i >= NE_TOT) return;
  int s, d; float w;
  if(i < NE){ s = eidx[i]; d = eidx[NE+i]; w = ew[i]; }
  else      { int n = i-NE; s=n; d=n; w = la[n]; }   // self-loop, weight = mean incoming
  int pos = off[d] + atomicAdd(&fill[d], 1);
  csrs[pos] = s; csrw[pos] = w;
}

// ---------------- MFMA GEMM: C = A @ W^T + bias ----------------
// AMODE: 0 = A f32 [M,K]; 1 = gather f32 (A[gidx]+remb[ridx], chunked rows);
//        2 = A bf16 [M,K].
// W: f32 [N,K] (torch Linear). OUTF32: write f32, else bf16.
// lens != null (proj): row=(b*NTT+t), t>=lens[b] -> bias only.
template<int AMODE, bool OUTF32>
__global__ __launch_bounds__(256) void k_gemm(
    const void* __restrict__ Av, const float* __restrict__ W, const float* __restrict__ bias,
    void* __restrict__ out,
    int M, int N, int K,
    const int* __restrict__ gidx, const int* __restrict__ ridx, const float* __restrict__ remb,
    int t0, int chk,
    const int* __restrict__ lens)
{
  int tid = threadIdx.x;
  int wid = tid >> 6, l = tid & 63;
  int lr = l & 15, lg = l >> 4;
  int bm = blockIdx.x*128 + wid*32;
  int bn = blockIdx.y*64;
  f32x4 acc[2][4] = {};
  int nk = K >> 5;
  for(int kt=0; kt<nk; ++kt){
    int k0 = kt*32 + lg*8;
    bf16x8 af[2];
    #pragma unroll
    for(int mi=0; mi<2; ++mi){
      int row = bm + mi*16 + lr;
      u16x8 v = {0,0,0,0,0,0,0,0};
      if(row < M){
        if constexpr(AMODE == 1){
          int b = row / chk, tt = row - b*chk;
          int gi = b*NTT + t0 + tt;
          const float* ar = (const float*)Av + (size_t)gidx[gi]*K + k0;
          const float* rr = remb + (size_t)ridx[gi]*K + k0;
          #pragma unroll
          for(int e=0;e<8;++e) v[e] = f2bf(ar[e] + rr[e]);
        } else if constexpr(AMODE == 0){
          const float* ar = (const float*)Av + (size_t)row*K + k0;
          #pragma unroll
          for(int e=0;e<8;++e) v[e] = f2bf(ar[e]);
        } else {
          v = *(const u16x8*)((const u16*)Av + (size_t)row*K + k0);
        }
      }
      af[mi] = __builtin_bit_cast(bf16x8, v);
    }
    #pragma unroll
    for(int nt=0; nt<4; ++nt){
      int col = bn + nt*16 + lr;
      const float* wr = W + (size_t)col*K + k0;
      u16x8 wv;
      #pragma unroll
      for(int e=0;e<8;++e) wv[e] = f2bf(wr[e]);
      bf16x8 bfr = __builtin_bit_cast(bf16x8, wv);
      acc[0][nt] = __builtin_amdgcn_mfma_f32_16x16x32_bf16(af[0], bfr, acc[0][nt], 0,0,0);
      acc[1][nt] = __builtin_amdgcn_mfma_f32_16x16x32_bf16(af[1], bfr, acc[1][nt], 0,0,0);
    }
  }
  #pragma unroll
  for(int mi=0; mi<2; ++mi){
    #pragma unroll
    for(int nt=0; nt<4; ++nt){
      int col = bn + nt*16 + lr;
      float bc = bias[col];
      #pragma unroll
      for(int r=0; r<4; ++r){
        int row = bm + mi*16 + lg*4 + r;
        if(row >= M) continue;
        float v = acc[mi][nt][r] + bc;
        if(lens){ int b = row/NTT; int t = row - b*NTT; if(t >= lens[b]) v = bc; }
        if constexpr(OUTF32) ((float*)out)[(size_t)row*N + col] = v;
        else                 ((u16*) out)[(size_t)row*N + col] = f2bf(v);
      }
    }
  }
}

// ---------------- GATv2 attention + aggregate + bias + ELU ----------------
__global__ __launch_bounds__(256) void k_attn(
    const int* __restrict__ off, const int* __restrict__ csrs, const float* __restrict__ csrw,
    const u16* __restrict__ xl, const u16* __restrict__ xr,
    const float* __restrict__ We, const float* __restrict__ att, const float* __restrict__ bias,
    float* __restrict__ hout)
{
  int wid = threadIdx.x >> 6, l = threadIdx.x & 63;
  int n = blockIdx.x*4 + wid;
  int d0 = 2*l;
  const unsigned int* xl2 = (const unsigned int*)xl;
  unsigned int xru = ((const unsigned int*)xr)[n*64 + l];
  float xrx = bf2f((u16)xru), xry = bf2f((u16)(xru>>16));
  float wex = We[d0],  wey = We[d0+1];
  float atx = att[d0], aty = att[d0+1];
  int p0 = off[n], p1 = off[n+1];
  float mx = -1e30f;
  for(int p=p0; p<p1; ++p){
    int s = csrs[p]; float w = csrw[p];
    unsigned int u = xl2[s*64 + l];
    float ax = bf2f((u16)u)       + xrx + w*wex;
    float ay = bf2f((u16)(u>>16)) + xry + w*wey;
    ax = ax > 0.f ? ax : 0.2f*ax;
    ay = ay > 0.f ? ay : 0.2f*ay;
    float c = ax*atx + ay*aty;
    c += __shfl_xor(c,1); c += __shfl_xor(c,2); c += __shfl_xor(c,4); c += __shfl_xor(c,8);
    mx = fmaxf(mx, c);
  }
  float den = 0.f, a0 = 0.f, a1 = 0.f;
  for(int p=p0; p<p1; ++p){
    int s = csrs[p]; float w = csrw[p];
    unsigned int u = xl2[s*64 + l];
    float xlx = bf2f((u16)u), xly = bf2f((u16)(u>>16));
    float ax = xlx + xrx + w*wex;
    float ay = xly + xry + w*wey;
    ax = ax > 0.f ? ax : 0.2f*ax;
    ay = ay > 0.f ? ay : 0.2f*ay;
    float c = ax*atx + ay*aty;
    c += __shfl_xor(c,1); c += __shfl_xor(c,2); c += __shfl_xor(c,4); c += __shfl_xor(c,8);
    float al = __expf(c - mx);
    den += al; a0 += al*xlx; a1 += al*xly;
  }
  float inv = 1.f/(den + 1e-16f);
  float o0 = a0*inv + bias[d0];
  float o1 = a1*inv + bias[d0+1];
  o0 = o0 > 0.f ? o0 : (__expf(o0) - 1.f);   // ELU
  o1 = o1 > 0.f ? o1 : (__expf(o1) - 1.f);
  hout[n*EMB + d0]   = o0;
  hout[n*EMB + d0+1] = o1;
}

// ---------------- GRU chunk: 16 blocks x 16 batch rows, 16 waves ----------------
// wave w owns hidden slice j in [16w,16w+16) for ALL 3 gates: 3 n-tiles x 8 k-frags
// = 24 bf16x8 fragments = 96 VGPRs -> fits the compiler's 128-VGPR budget (1024-thr
// block caps at 128), so Whh stays register-resident with NO spill.
// xg staged via global_load_lds; f32 state across chunks in hsave.

#define DECLW(g) bf16x8 wf_##g##_0, wf_##g##_1, wf_##g##_2, wf_##g##_3, \
                        wf_##g##_4, wf_##g##_5, wf_##g##_6, wf_##g##_7;

#define LDW1(g,kt) { const float* wp = wr + (kt)*32 + lg*8; u16x8 wv; \
  _Pragma("unroll") for(int e=0;e<8;++e) wv[e]=f2bf(wp[e]); \
  wf_##g##_##kt = __builtin_bit_cast(bf16x8, keepf(__builtin_bit_cast(f32x4, wv))); }

#define LDW(g) { int nrow = (g)*256 + wid*16 + lr; \
  bh[g] = bhh[nrow]; const float* wr = Whh + (size_t)nrow*RH; \
  LDW1(g,0) LDW1(g,1) LDW1(g,2) LDW1(g,3) LDW1(g,4) LDW1(g,5) LDW1(g,6) LDW1(g,7) }

#define MST(kt) { int kg = ((kt)*4 + lg) ^ lr; \
  bf16x8 af = __builtin_bit_cast(bf16x8, *(const u16x8*)(lds_h + lr*RH + kg*8)); \
  accR = __builtin_amdgcn_mfma_f32_16x16x32_bf16(af, wf_0_##kt, accR, 0,0,0); \
  accZ = __builtin_amdgcn_mfma_f32_16x16x32_bf16(af, wf_1_##kt, accZ, 0,0,0); \
  accN = __builtin_amdgcn_mfma_f32_16x16x32_bf16(af, wf_2_##kt, accN, 0,0,0); }

__global__ __launch_bounds__(1024) void k_gru(
    const u16* __restrict__ xgc, const float* __restrict__ Whh, const float* __restrict__ bhh,
    const int* __restrict__ lens, u16* __restrict__ hseq, float* __restrict__ hsave,
    int t0, int t1, int chk)
{
  int tid = threadIdx.x;
  int wid = tid >> 6, l = tid & 63;
  int lr = l & 15, lg = l >> 4;
  int b0 = blockIdx.x*16;
  __shared__ u16 lds_h[16*RH];     // 8 KB
  __shared__ u16 lds_xg[16*G3];    // 24 KB

  int maxlen = 0;
  for(int i=0;i<16;++i){ int v = lens[b0+i]; maxlen = v>maxlen ? v : maxlen; }
  int tend = maxlen < t1 ? maxlen : t1;

  // Whh B-fragments (f32 -> bf16): 24 named locals, 96 VGPRs, pinned via keepf
  float bh[3];
  DECLW(0) DECLW(1) DECLW(2)
  LDW(0) LDW(1) LDW(2)

  // h init (swizzled lds_h: physical granule c of row holds logical granule c^row)
  if(tid < 512){
    int row = tid>>5, cl = tid&31, cg = cl^row;
    u16x8 v = {0,0,0,0,0,0,0,0};
    if(t0 > 0){
      const float* hp = hsave + (size_t)(b0+row)*RH + cg*8;
      #pragma unroll
      for(int e=0;e<8;++e) v[e] = f2bf(hp[e]);
    }
    *(u16x8*)(lds_h + tid*8) = v;
  }
  float hst[4];
  #pragma unroll
  for(int r=0;r<4;++r){
    int j = wid*16 + lr, row = lg*4 + r;
    hst[r] = (t0>0) ? hsave[(size_t)(b0+row)*RH + j] : 0.f;
  }

  // loop-invariant staging addresses (pre-swizzled global source, linear LDS dest)
  const u16* xsrc0; const u16* xsrc1;
  {
    int p0s = tid,                 r0 = p0s/96, c0 = (p0s - r0*96) ^ r0;
    int p1s = 1024 + (tid & 511),  r1 = p1s/96, c1 = (p1s - r1*96) ^ r1;
    xsrc0 = xgc + ((size_t)((b0+r0)*chk))*G3 + c0*8;
    xsrc1 = xgc + ((size_t)((b0+r1)*chk))*G3 + c1*8;
  }
  u16* lbase0 = lds_xg + (wid*64)*8;
  u16* lbase1 = lds_xg + (1024 + wid*64)*8;
  u16* llane0 = lds_xg + tid*8;
  u16* llane1 = lds_xg + (1024 + (tid & 511))*8;

  int orow = (tid & 511)>>5, ocl = tid&31, ocg = ocl^orow;
  int mylen = lens[b0 + orow];
  u16* outp = hseq + ((size_t)((b0+orow)*NTT + t0))*RH + ocg*8;
  __syncthreads();

  for(int t=t0; t<tend; ++t){
    // async-stage xg(t) into lds_xg (lands by the next barrier)
    stage16(xsrc0, lbase0, llane0);
    if(wid < 8) stage16(xsrc1, lbase1, llane1);
    xsrc0 += G3; xsrc1 += G3;

    // hg = h @ Whh^T  (reads lds_h; weights in registers)
    f32x4 accR = {}, accZ = {}, accN = {};
    MST(0) MST(1) MST(2) MST(3) MST(4) MST(5) MST(6) MST(7)

    asm volatile("s_waitcnt vmcnt(0)" ::: "memory");
    __syncthreads();                       // lds_xg ready (all waves), lds_h reads done

    // gates: lane holds rows lg*4+r for hidden j = wid*16 + lr
    {
      int j = wid*16 + lr;
      int jgr = j>>3, jo = j&7;
      #pragma unroll
      for(int r=0;r<4;++r){
        int row = lg*4 + r;
        const u16* xrow = lds_xg + row*G3;
        float xrv = bf2f(xrow[((jgr     )^row)*8 + jo]);
        float xzv = bf2f(xrow[((jgr + 32)^row)*8 + jo]);
        float xnv = bf2f(xrow[((jgr + 64)^row)*8 + jo]);
        float hr = accR[r] + bh[0];
        float hz = accZ[r] + bh[1];
        float hn = accN[r] + bh[2];
        float rg = 1.f/(1.f + __expf(-(xrv + hr)));
        float zg = 1.f/(1.f + __expf(-(xzv + hz)));
        float nn = xnv + rg*hn;
        float tg = 1.f - 2.f/(__expf(2.f*nn) + 1.f);   // tanh
        float hv = (1.f - zg)*tg + zg*hst[r];
        hst[r] = hv;
        lds_h[row*RH + (jgr^row)*8 + jo] = f2bf(hv);
      }
    }
    __syncthreads();                       // lds_h fully written

    // copy-out h(t) -> hseq (zeros for t >= len[row])
    if(tid < 512){
      u16x8 v = {0,0,0,0,0,0,0,0};
      if(t < mylen) v = *(const u16x8*)(lds_h + tid*8);
      *(u16x8*)outp = v;
    }
    outp += RH;
  }

  // zero-fill [max(tend,t0), t1) so hseq is fully written & deterministic
  if(tid < 512){
    u16* zp = outp;
    for(int t = (tend > t0 ? tend : t0); t < t1; ++t){
      u16x8 z = {0,0,0,0,0,0,0,0};
      *(u16x8*)zp = z;
      zp += RH;
    }
  }

  // save exact f32 state for next chunk
  #pragma unroll
  for(int r=0;r<4;++r){
    int j = wid*16 + lr, row = lg*4 + r;
    hsave[(size_t)(b0+row)*RH + j] = hst[r];
  }
}

// ---------------- launcher ----------------
extern "C" void kernel_launch(void* const* d_in, const int* in_sizes, int n_in,
                              void* d_out, int out_size, void* d_ws, size_t ws_size,
                              hipStream_t stream){
  (void)in_sizes; (void)n_in; (void)out_size;
  const int*   skills = (const int*)d_in[0];
  const int*   resp   = (const int*)d_in[1];
  const int*   lens   = (const int*)d_in[2];
  const int*   eidx   = (const int*)d_in[3];
  const float* ew     = (const float*)d_in[4];
  const float* emb    = (const float*)d_in[5];
  const float* gW[2][7];
  for(int l2=0;l2<2;++l2) for(int j=0;j<7;++j) gW[l2][j] = (const float*)d_in[6 + l2*7 + j];
  const float* remb  = (const float*)d_in[20];
  const float* Wih   = (const float*)d_in[21];
  const float* Whh   = (const float*)d_in[22];
  const float* bih   = (const float*)d_in[23];
  const float* bhh   = (const float*)d_in[24];
  const float* projW = (const float*)d_in[25];
  const float* projb = (const float*)d_in[26];

  char* p = (char*)d_ws;
  size_t o = 0;
  auto take = [&](size_t bytes)->char*{ char* r = p + o; o = (o + bytes + 255) & ~(size_t)255; return r; };
  int*   deg  = (int*)  take(4*N_NODES);
  int*   fill = (int*)  take(4*N_NODES);
  float* wsum = (float*)take(4*N_NODES);
  size_t zbytes = o;                        // deg+fill+wsum zeroed each call
  int*   off   = (int*)  take(4*(N_NODES+1));
  int*   csrs  = (int*)  take(4*NE_TOT);
  float* csrw  = (float*)take(4*NE_TOT);
  u16*   xl    = (u16*)  take(2UL*N_NODES*EMB);
  u16*   xr    = (u16*)  take(2UL*N_NODES*EMB);
  float* h1    = (float*)take(4UL*N_NODES*EMB);
  float* hsave = (float*)take(4UL*NB*RH);
  u16*   hseq  = (u16*)  take(2UL*NB*NTT*RH);
  size_t fixed_end = o;
  // xg chunk length: largest of {200,100,50,25} that fits ws_size
  int chk = 200;
  while(chk > 25 && fixed_end + 2UL*NB*(size_t)chk*G3 > ws_size) chk /= 2;
  u16*   xgc  = (u16*)  take(2UL*NB*(size_t)chk*G3);

  float* outP = (float*)d_out;                     // h_proj [256,200,128] f32
  float* outE = outP + (size_t)NB*NTT*EMB;         // skill_embs [10000,128] f32

  hipMemsetAsync(d_ws, 0, zbytes, stream);
  k_deg<<<(NE+255)/256, 256, 0, stream>>>(eidx, ew, deg, wsum);
  k_scan<<<1, 1024, 0, stream>>>(deg, wsum, off);
  k_scatter<<<(NE_TOT+255)/256, 256, 0, stream>>>(eidx, ew, wsum, off, fill, csrs, csrw);

  dim3 gN((N_NODES+127)/128, EMB/64);
  // layer 0 (A = emb f32 -> xl/xr bf16)
  k_gemm<0,false><<<gN, 256, 0, stream>>>(emb, gW[0][0], gW[0][1], xl, N_NODES, EMB, EMB,
                                 nullptr, nullptr, nullptr, 0,0, nullptr);
  k_gemm<0,false><<<gN, 256, 0, stream>>>(emb, gW[0][2], gW[0][3], xr, N_NODES, EMB, EMB,
                                 nullptr, nullptr, nullptr, 0,0, nullptr);
  k_attn<<<N_NODES/4, 256, 0, stream>>>(off, csrs, csrw, xl, xr, gW[0][4], gW[0][5], gW[0][6], h1);
  // layer 1 (A = h1 f32)
  k_gemm<0,false><<<gN, 256, 0, stream>>>(h1, gW[1][0], gW[1][1], xl, N_NODES, EMB, EMB,
                                 nullptr, nullptr, nullptr, 0,0, nullptr);
  k_gemm<0,false><<<gN, 256, 0, stream>>>(h1, gW[1][2], gW[1][3], xr, N_NODES, EMB, EMB,
                                 nullptr, nullptr, nullptr, 0,0, nullptr);
  k_attn<<<N_NODES/4, 256, 0, stream>>>(off, csrs, csrw, xl, xr, gW[1][4], gW[1][5], gW[1][6], outE);

  // chunked: xg = (skill_embs[skills]+resp_emb[resp]) @ Wih^T + bih, then GRU chunk
  for(int t0=0; t0<NTT; t0+=chk){
    k_gemm<1,false><<<dim3(NB*chk/128, G3/64), 256, 0, stream>>>(outE, Wih, bih, xgc,
                                 NB*chk, G3, EMB, skills, resp, remb, t0, chk, nullptr);
    k_gru<<<16, 1024, 0, stream>>>(xgc, Whh, bhh, lens, hseq, hsave, t0, t0+chk, chk);
  }
  // proj: A = hseq bf16, out f32 (+ lens mask; hseq rows t>=len are exact zeros)
  k_gemm<2,true><<<dim3(NB*NTT/128, EMB/64), 256, 0, stream>>>(hseq, projW, projb, outP,
                                 NB*NTT, EMB, RH,
                                 nullptr, nullptr, nullptr, 0,0, lens);
}